// Round 2
// 483.881 us; speedup vs baseline: 1.5324x; 1.5324x over previous
//
#include <hip/hip_runtime.h>
#include <hip/hip_bf16.h>

#define C 48
#define C4 192
#define HW 192
#define NPIX (HW * HW)          // 36864
#define BATCH 8
#define CNT (BATCH * NPIX)      // 294912 samples per channel for BN

// Workspace layout. Total ~85.6 MB.
#define APRE_OFF   0ull
#define G_OFF      14155776ull
#define STATS_OFF  14229504ull
#define M2_OFF     14229696ull
#define MIDT_BYTE  57213696ull
#define WB_BYTE    85525248ull

typedef __attribute__((ext_vector_type(8))) short short8;
typedef __attribute__((ext_vector_type(4))) float f32x4;

static __device__ __forceinline__ unsigned pkbf(float a, float b) {
    union { __hip_bfloat162 h; unsigned u; } t;
    t.h = __float22bfloat162_rn(make_float2(a, b));
    return t.u;                                   // low16 = bf16(a), high16 = bf16(b)
}
static __device__ __forceinline__ float lo2f(unsigned p) { return __uint_as_float(p << 16); }
static __device__ __forceinline__ float hi2f(unsigned p) { return __uint_as_float(p & 0xffff0000u); }
static __device__ __forceinline__ short f2bfs(float f) { return (short)(pkbf(f, f) & 0xffffu); }

// ---------------------------------------------------------------- k_gram_mfma
// G[s,b,c,d] = sum_n X0[b,c,n] * Xs[b,d,n] via bf16 hi/lo split MFMA (3 products).
// Block: 512-n chunk, all 48x192 outputs. LDS: [192 ch][64 n] hi+lo, stride 72.
__global__ __launch_bounds__(256) void k_gram_mfma(
    const float* __restrict__ x0, const float* __restrict__ x1,
    const float* __restrict__ x2, const float* __restrict__ x3,
    float* __restrict__ G)
{
    __shared__ short hibuf[C4 * 72];
    __shared__ short lobuf[C4 * 72];
    int b = blockIdx.y;
    int n0 = blockIdx.x * 512;
    int tid = threadIdx.x;
    int wid = tid >> 6, lane = tid & 63, col = lane & 15, quad = lane >> 4;

    const float* x0b = x0 + (size_t)b * C * NPIX;
    const float* x1b = x1 + (size_t)b * C * NPIX;
    const float* x2b = x2 + (size_t)b * C * NPIX;
    const float* x3b = x3 + (size_t)b * C * NPIX;

    f32x4 acc[3][3];
#pragma unroll
    for (int mt = 0; mt < 3; ++mt)
#pragma unroll
        for (int nt = 0; nt < 3; ++nt)
            acc[mt][nt] = (f32x4){0.f, 0.f, 0.f, 0.f};

    int scr = tid >> 4;            // 0..15: ch sub-row
    int n4 = (tid & 15) * 4;       // n offset within 64

    for (int sub = 0; sub < 8; ++sub) {
        int nb = n0 + sub * 64;
        __syncthreads();
#pragma unroll
        for (int it = 0; it < 12; ++it) {
            int ch = scr + it * 16;
            int s = ch / C, c = ch - s * C;
            const float* xp = (s == 0) ? x0b : (s == 1) ? x1b : (s == 2) ? x2b : x3b;
            float4 v = *(const float4*)(xp + (size_t)c * NPIX + nb + n4);
            unsigned h01 = pkbf(v.x, v.y), h23 = pkbf(v.z, v.w);
            float r0 = v.x - lo2f(h01), r1 = v.y - hi2f(h01);
            float r2 = v.z - lo2f(h23), r3 = v.w - hi2f(h23);
            unsigned l01 = pkbf(r0, r1), l23 = pkbf(r2, r3);
            *(unsigned*)&hibuf[ch * 72 + n4]     = h01;
            *(unsigned*)&hibuf[ch * 72 + n4 + 2] = h23;
            *(unsigned*)&lobuf[ch * 72 + n4]     = l01;
            *(unsigned*)&lobuf[ch * 72 + n4 + 2] = l23;
        }
        __syncthreads();
#pragma unroll
        for (int kb = 0; kb < 2; ++kb) {
            int ko = kb * 32 + quad * 8;
            short8 ah[3], al[3], bh[3], bl[3];
#pragma unroll
            for (int mt = 0; mt < 3; ++mt) {
                ah[mt] = *(const short8*)&hibuf[(mt * 16 + col) * 72 + ko];
                al[mt] = *(const short8*)&lobuf[(mt * 16 + col) * 72 + ko];
            }
#pragma unroll
            for (int nt = 0; nt < 3; ++nt) {
                int row = (wid * 3 + nt) * 16 + col;
                bh[nt] = *(const short8*)&hibuf[row * 72 + ko];
                bl[nt] = *(const short8*)&lobuf[row * 72 + ko];
            }
#pragma unroll
            for (int mt = 0; mt < 3; ++mt)
#pragma unroll
                for (int nt = 0; nt < 3; ++nt) {
                    acc[mt][nt] = __builtin_amdgcn_mfma_f32_16x16x32_bf16(
                        ah[mt], bh[nt], acc[mt][nt], 0, 0, 0);
                    acc[mt][nt] = __builtin_amdgcn_mfma_f32_16x16x32_bf16(
                        ah[mt], bl[nt], acc[mt][nt], 0, 0, 0);
                    acc[mt][nt] = __builtin_amdgcn_mfma_f32_16x16x32_bf16(
                        al[mt], bh[nt], acc[mt][nt], 0, 0, 0);
                }
        }
    }
#pragma unroll
    for (int mt = 0; mt < 3; ++mt)
#pragma unroll
        for (int nt = 0; nt < 3; ++nt) {
            int g = (wid * 3 + nt) * 16 + col;        // 0..191 = s*48 + d
            int s = g / C, d = g - s * C;
#pragma unroll
            for (int j = 0; j < 4; ++j) {
                int c = mt * 16 + quad * 4 + j;
                atomicAdd(&G[(((size_t)s * BATCH + b) * C + c) * C + d],
                          acc[mt][nt][j]);
            }
        }
}

// ---------------------------------------------------------------- k_small
__global__ __launch_bounds__(256) void k_small(
    const float* __restrict__ G,
    const float* __restrict__ Wa, const float* __restrict__ Wb,
    const float* __restrict__ Wc, const float* __restrict__ Wd,
    const float* __restrict__ fuse_w, float* __restrict__ M2g)
{
    int s = blockIdx.x, b = blockIdx.y;
    const float* Ws = (s == 0) ? Wa : (s == 1) ? Wb : (s == 2) ? Wc : Wd;

    __shared__ float g[C * C], wsm[C * C], wam[C * C], fw[C * C];
    __shared__ float t[C * C], e[C * C], m[C * C];
    int tid = threadIdx.x;

    const float* Gb = G + ((size_t)s * BATCH + b) * C * C;
    for (int k = tid; k < C * C; k += 256) {
        g[k] = Gb[k];
        wsm[k] = Ws[k];
        wam[k] = Wa[k];
        int o = k / C, c = k % C;
        fw[k] = fuse_w[(size_t)o * C4 + s * C + c];
    }
    __syncthreads();

    for (int k = tid; k < C * C; k += 256) {
        int c = k / C, d = k % C;
        float a = 0.f;
        for (int q = 0; q < C; ++q) a += g[c * C + q] * wsm[d * C + q];
        t[k] = a;
    }
    __syncthreads();
    for (int k = tid; k < C * C; k += 256) {
        int c = k / C, d = k % C;
        float a = 0.f;
        for (int q = 0; q < C; ++q) a += wam[c * C + q] * t[q * C + d];
        e[k] = a;
    }
    __syncthreads();
    if (tid < C) {
        int c = tid;
        float mn = e[c * C];
        for (int d = 1; d < C; ++d) mn = fminf(mn, e[c * C + d]);
        float sum = 0.f;
        for (int d = 0; d < C; ++d) {
            float v = __expf(mn - e[c * C + d]);
            e[c * C + d] = v;
            sum += v;
        }
        float inv = 1.0f / sum;
        for (int d = 0; d < C; ++d) e[c * C + d] *= inv;
    }
    __syncthreads();
    for (int k = tid; k < C * C; k += 256) {
        int d = k / C, o = k % C;
        float a = 0.f;
        for (int q = 0; q < C; ++q) a += fw[o * C + q] * e[q * C + d];
        m[k] = a;
    }
    __syncthreads();
    float* out = M2g + ((size_t)b * 4 + s) * C * C;
    for (int k = tid; k < C * C; k += 256) {
        int c = k / C, o = k % C;
        float a = 0.f;
        for (int q = 0; q < C; ++q) a += wsm[q * C + c] * m[q * C + o];
        out[k] = a;
    }
}

// ---------------------------------------------------------------- k_apply_mfma
// apre[b,o,n] = sum_{k=0..191} M2[b][k][o] * X[k][n] + fuse_b[o]  via MFMA.
// Rewrite vs prior version:
//  * X tiles (64 n x 192 ch) staged in LDS via coalesced float4 loads
//    (2 adjacent channels x 4 pixels per thread -> channel-pair-packed dwords,
//    transposed [n][ch] rows). No more 8x scalar stride-NPIX gathers.
//  * Row stride 512 B + within-row XOR swizzle f=((row>>1)^(row>>2))&7 applied
//    as x ^= f<<4: both ds_write_b32 (2-way) and ds_read_b128 (8 acc/bank) hit
//    the wave64 bank-conflict minimum; bijective, in-bounds by construction.
//  * Compact K=192 (6 kq, channel runs may cross source boundaries inside LDS)
//    -> 18 MFMA per 16-n slice instead of 24 (no zero padding).
//  * Chunk 256 n -> grid 144x8 = 1152 blocks (was 576): 4.5 blocks/CU.
//  * BN stats: block-level LDS reduction, then 96 global atomics per block.
static __device__ __forceinline__ unsigned ladr(unsigned row, unsigned x) {
    unsigned f = ((row >> 1) ^ (row >> 2)) & 7;
    return (row << 9) | (x ^ (f << 4));
}

__global__ __launch_bounds__(256) void k_apply_mfma(
    const float* __restrict__ x0, const float* __restrict__ x1,
    const float* __restrict__ x2, const float* __restrict__ x3,
    const float* __restrict__ M2g, const float* __restrict__ fuse_b,
    float* __restrict__ apre, float* __restrict__ stats)
{
    __shared__ __align__(16) char xbuf[64 * 512];  // A-phase: [48 o][k192]; tiles: [64 n][192 ch]
    __shared__ float sst[96];
    char* lb = xbuf;

    int b = blockIdx.y;
    int n0 = blockIdx.x * 256;
    int tid = threadIdx.x;
    int wid = tid >> 6, lane = tid & 63, col = lane & 15, quad = lane >> 4;

    const float* x0b = x0 + (size_t)b * C * NPIX;
    const float* x1b = x1 + (size_t)b * C * NPIX;
    const float* x2b = x2 + (size_t)b * C * NPIX;
    const float* x3b = x3 + (size_t)b * C * NPIX;

    if (tid < 96) sst[tid] = 0.f;

    // ---- A = M2 (k = s*48+c compact, rows = o) into LDS as bf16
    const float* Mb = M2g + (size_t)b * 4 * C * C;
    for (int e = tid; e < 48 * 192; e += 256) {
        int k = e / 48, o = e - k * 48;            // consecutive lanes -> consecutive o (coalesced)
        *(short*)(lb + ladr(o, k * 2)) = f2bfs(Mb[(size_t)k * 48 + o]);
    }
    __syncthreads();

    short8 afr[3][6];
#pragma unroll
    for (int mt = 0; mt < 3; ++mt)
#pragma unroll
        for (int kq = 0; kq < 6; ++kq)
            afr[mt][kq] = *(const short8*)(lb + ladr(mt * 16 + col, kq * 64 + quad * 16));

    float fbv[3][4];
#pragma unroll
    for (int mt = 0; mt < 3; ++mt)
#pragma unroll
        for (int j = 0; j < 4; ++j)
            fbv[mt][j] = fuse_b[mt * 16 + quad * 4 + j];

    float s1[3][4] = {}, s2[3][4] = {};
    int nl = (wid << 4) + col;

    for (int sub = 0; sub < 4; ++sub) {
        int nb = n0 + sub * 64;
        __syncthreads();                            // prior tile's reads (or afr hoist) done
#pragma unroll
        for (int it = 0; it < 6; ++it) {
            int ef = tid + it * 256;                // 0..1535
            int p  = ef >> 4;                       // channel pair 0..95
            int nq = (ef & 15) << 2;                // 0..60
            int s  = p / 24;
            int c2 = (p - s * 24) * 2;
            const float* xp = ((s == 0) ? x0b : (s == 1) ? x1b : (s == 2) ? x2b : x3b)
                              + (size_t)c2 * NPIX + nb + nq;
            float4 va = *(const float4*)xp;         // channel c2,   n..n+3
            float4 vb = *(const float4*)(xp + NPIX);// channel c2+1, n..n+3
            unsigned p4 = (unsigned)p * 4;
            *(unsigned*)(lb + ladr(nq + 0, p4)) = pkbf(va.x, vb.x);
            *(unsigned*)(lb + ladr(nq + 1, p4)) = pkbf(va.y, vb.y);
            *(unsigned*)(lb + ladr(nq + 2, p4)) = pkbf(va.z, vb.z);
            *(unsigned*)(lb + ladr(nq + 3, p4)) = pkbf(va.w, vb.w);
        }
        __syncthreads();

        f32x4 acc[3];
        acc[0] = (f32x4){0.f, 0.f, 0.f, 0.f};
        acc[1] = (f32x4){0.f, 0.f, 0.f, 0.f};
        acc[2] = (f32x4){0.f, 0.f, 0.f, 0.f};
#pragma unroll
        for (int kq = 0; kq < 6; ++kq) {
            short8 bfr = *(const short8*)(lb + ladr(nl, kq * 64 + quad * 16));
            acc[0] = __builtin_amdgcn_mfma_f32_16x16x32_bf16(afr[0][kq], bfr, acc[0], 0, 0, 0);
            acc[1] = __builtin_amdgcn_mfma_f32_16x16x32_bf16(afr[1][kq], bfr, acc[1], 0, 0, 0);
            acc[2] = __builtin_amdgcn_mfma_f32_16x16x32_bf16(afr[2][kq], bfr, acc[2], 0, 0, 0);
        }

        int n = nb + nl;
#pragma unroll
        for (int mt = 0; mt < 3; ++mt)
#pragma unroll
            for (int j = 0; j < 4; ++j) {
                int o = mt * 16 + quad * 4 + j;
                float val = acc[mt][j] + fbv[mt][j];
                apre[((size_t)b * C + o) * NPIX + n] = val;
                s1[mt][j] += val;
                s2[mt][j] += val * val;
            }
    }

#pragma unroll
    for (int mt = 0; mt < 3; ++mt)
#pragma unroll
        for (int j = 0; j < 4; ++j) {
            float a = s1[mt][j], q = s2[mt][j];
#pragma unroll
            for (int off = 8; off; off >>= 1) {
                a += __shfl_down(a, off, 16);
                q += __shfl_down(q, off, 16);
            }
            if (col == 0) {
                int o = mt * 16 + quad * 4 + j;
                atomicAdd(&sst[o], a);
                atomicAdd(&sst[48 + o], q);
            }
        }
    __syncthreads();
    if (tid < 96) atomicAdd(&stats[tid], sst[tid]);   // stats[o], stats[C+o] are contiguous
}

// ---------------------------------------------------------------- k_bn1t
// mid_t[b,px,c] = bf16(gamma_cam*relu(BN(apre)) + input); LDS tile-transpose
// makes the global bf16 store a contiguous short4 stream.
__global__ __launch_bounds__(256) void k_bn1t(
    const float* __restrict__ apre, const float* __restrict__ inp,
    const float* __restrict__ stats, const float* __restrict__ gamma,
    const float* __restrict__ beta, const float* __restrict__ gcam,
    short* __restrict__ mid_t)
{
    __shared__ short t[64 * C];     // [px_local][c]
    int b = blockIdx.y;
    int n0 = blockIdx.x * 64;
    int tid = threadIdx.x;
    const float invc = 1.0f / (float)CNT;
    float g = gcam[0];

#pragma unroll
    for (int it = 0; it < 3; ++it) {
        int e = tid + it * 256;                 // 0..767 = 48 ch x 16 px-quads
        int c = e >> 4, pq = (e & 15) * 4;
        float mu = stats[c] * invc;
        float var = stats[C + c] * invc - mu * mu;
        float sc = gamma[c] * rsqrtf(var + 1e-5f);
        float be = beta[c] - mu * sc;
        size_t base = ((size_t)b * C + c) * NPIX + n0 + pq;
        float4 v = *(const float4*)(apre + base);
        float4 x = *(const float4*)(inp + base);
        t[(pq + 0) * C + c] = f2bfs(fmaxf(v.x * sc + be, 0.f) * g + x.x);
        t[(pq + 1) * C + c] = f2bfs(fmaxf(v.y * sc + be, 0.f) * g + x.y);
        t[(pq + 2) * C + c] = f2bfs(fmaxf(v.z * sc + be, 0.f) * g + x.z);
        t[(pq + 3) * C + c] = f2bfs(fmaxf(v.w * sc + be, 0.f) * g + x.w);
    }
    __syncthreads();
    short* mb = mid_t + ((size_t)b * NPIX + n0) * C;
#pragma unroll
    for (int it = 0; it < 3; ++it) {
        int e = tid + it * 256;                 // contiguous: row = 12 short4s
        *(short4*)(mb + e * 4) = *(const short4*)&t[e * 4];
    }
}

// ---------------------------------------------------------------- k_prep
__global__ __launch_bounds__(256) void k_prep(
    const float* __restrict__ outw, short* __restrict__ Wb)
{
    int idx = blockIdx.x * 256 + threadIdx.x;
    if (idx >= 9 * 48 * 64) return;
    int i = idx & 63;
    int o = (idx >> 6) % 48;
    int tap = idx / (64 * 48);
    float v = (i < C) ? outw[((size_t)o * C + i) * 9 + tap] : 0.f;
    Wb[idx] = f2bfs(v);
}

// ---------------------------------------------------------------- k_conv_mfma
__global__ __launch_bounds__(256) void k_conv_mfma(
    const short* __restrict__ mid_t, const short* __restrict__ Wb,
    const float* __restrict__ bias, float* __restrict__ out,
    float* __restrict__ stats)
{
    __shared__ short xl[324 * 72];
    __shared__ float sst[96];
    int b = blockIdx.y;
    int ty = blockIdx.x / 12, tx = blockIdx.x % 12;
    int h0 = ty * 16, w0 = tx * 16;
    int tid = threadIdx.x;

    if (tid < 96) sst[tid] = 0.f;

    for (int ch = tid; ch < 2916; ch += 256) {
        int lpx = ch / 9, part = ch % 9;
        int hh = h0 - 1 + lpx / 18, ww = w0 - 1 + lpx % 18;
        short8 v = {0, 0, 0, 0, 0, 0, 0, 0};
        if (part < 6 && hh >= 0 && hh < HW && ww >= 0 && ww < HW)
            v = *(const short8*)(mid_t + ((size_t)b * NPIX + hh * HW + ww) * C + part * 8);
        *(short8*)(xl + lpx * 72 + part * 8) = v;
    }
    __syncthreads();

    int wid = tid >> 6, lane = tid & 63;
    int col = lane & 15, quad = lane >> 4;

    f32x4 acc[3][4];
#pragma unroll
    for (int mt = 0; mt < 3; ++mt)
#pragma unroll
        for (int rr = 0; rr < 4; ++rr)
            acc[mt][rr] = (f32x4){0.f, 0.f, 0.f, 0.f};

#pragma unroll
    for (int tap = 0; tap < 9; ++tap) {
        int dh = tap / 3, dw = tap % 3;
#pragma unroll
        for (int kb = 0; kb < 2; ++kb) {
            short8 afr[3];
#pragma unroll
            for (int mt = 0; mt < 3; ++mt)
                afr[mt] = *(const short8*)(Wb + ((size_t)(tap * 48 + mt * 16 + col)) * 64
                                               + kb * 32 + quad * 8);
#pragma unroll
            for (int rr = 0; rr < 4; ++rr) {
                int r = wid * 4 + rr;
                int lpx = (r + dh) * 18 + col + dw;
                short8 bfr = *(const short8*)(xl + lpx * 72 + kb * 32 + quad * 8);
#pragma unroll
                for (int mt = 0; mt < 3; ++mt)
                    acc[mt][rr] = __builtin_amdgcn_mfma_f32_16x16x32_bf16(
                        afr[mt], bfr, acc[mt][rr], 0, 0, 0);
            }
        }
    }

    float s1[3][4] = {}, s2[3][4] = {};
#pragma unroll
    for (int mt = 0; mt < 3; ++mt)
#pragma unroll
        for (int rr = 0; rr < 4; ++rr) {
            int r = wid * 4 + rr;
            f32x4 v = acc[mt][rr];
#pragma unroll
            for (int j = 0; j < 4; ++j) {
                int o = mt * 16 + quad * 4 + j;
                float val = v[j] + bias[o];
                out[((size_t)b * C + o) * NPIX + (h0 + r) * HW + w0 + col] = val;
                s1[mt][j] += val;
                s2[mt][j] += val * val;
            }
        }
#pragma unroll
    for (int mt = 0; mt < 3; ++mt)
#pragma unroll
        for (int j = 0; j < 4; ++j) {
            float a = s1[mt][j], q = s2[mt][j];
#pragma unroll
            for (int off = 8; off; off >>= 1) {
                a += __shfl_down(a, off, 16);
                q += __shfl_down(q, off, 16);
            }
            if (col == 0) {
                int o = mt * 16 + quad * 4 + j;
                atomicAdd(&sst[o], a);
                atomicAdd(&sst[48 + o], q);
            }
        }
    __syncthreads();
    if (tid < 48)       atomicAdd(&stats[2 * C + tid], sst[tid]);
    else if (tid < 96)  atomicAdd(&stats[3 * C + tid - 48], sst[tid]);
}

// ---------------------------------------------------------------- k_bn2
__global__ __launch_bounds__(256) void k_bn2(
    float* __restrict__ out, const float* __restrict__ stats,
    const float* __restrict__ gamma, const float* __restrict__ beta)
{
    size_t i = ((size_t)blockIdx.x * 256 + threadIdx.x) * 4;
    int c = (int)((i / NPIX) % C);
    const float invc = 1.0f / (float)CNT;
    float mu = stats[2 * C + c] * invc;
    float var = stats[3 * C + c] * invc - mu * mu;
    float sc = gamma[c] * rsqrtf(var + 1e-5f);
    float be = beta[c] - mu * sc;

    float4 v = *(float4*)(out + i);
    v.x = fmaxf(v.x * sc + be, 0.f);
    v.y = fmaxf(v.y * sc + be, 0.f);
    v.z = fmaxf(v.z * sc + be, 0.f);
    v.w = fmaxf(v.w * sc + be, 0.f);
    *(float4*)(out + i) = v;
}

// ---------------------------------------------------------------- launch
extern "C" void kernel_launch(void* const* d_in, const int* in_sizes, int n_in,
                              void* d_out, int out_size, void* d_ws, size_t ws_size,
                              hipStream_t stream)
{
    const float* inp   = (const float*)d_in[0];
    const float* fb    = (const float*)d_in[1];
    const float* fc    = (const float*)d_in[2];
    const float* fd    = (const float*)d_in[3];
    const float* Wa    = (const float*)d_in[4];
    const float* Wbm   = (const float*)d_in[5];
    const float* Wcm   = (const float*)d_in[6];
    const float* Wdm   = (const float*)d_in[7];
    const float* fusew = (const float*)d_in[8];
    const float* fuseb = (const float*)d_in[9];
    const float* fgam  = (const float*)d_in[10];
    const float* fbet  = (const float*)d_in[11];
    const float* gcam  = (const float*)d_in[12];
    const float* outw  = (const float*)d_in[13];
    const float* outb  = (const float*)d_in[14];
    const float* ogam  = (const float*)d_in[15];
    const float* obet  = (const float*)d_in[16];

    float* ws    = (float*)d_ws;
    float* apre  = ws + APRE_OFF;
    float* G     = ws + G_OFF;
    float* stats = ws + STATS_OFF;
    float* M2g   = ws + M2_OFF;
    short* mid_t = (short*)((char*)d_ws + MIDT_BYTE);
    short* Wb    = (short*)((char*)d_ws + WB_BYTE);
    float* out   = (float*)d_out;

    hipMemsetAsync(G, 0, (73728ull + 192ull) * sizeof(float), stream);

    k_prep<<<108, 256, 0, stream>>>(outw, Wb);
    k_gram_mfma<<<dim3(72, BATCH), 256, 0, stream>>>(inp, fb, fc, fd, G);
    k_small<<<dim3(4, BATCH), 256, 0, stream>>>(G, Wa, Wbm, Wcm, Wdm, fusew, M2g);
    k_apply_mfma<<<dim3(144, BATCH), 256, 0, stream>>>(inp, fb, fc, fd, M2g, fuseb, apre, stats);
    k_bn1t<<<dim3(576, BATCH), 256, 0, stream>>>(apre, inp, stats, fgam, fbet, gcam, mid_t);
    k_conv_mfma<<<dim3(144, BATCH), 256, 0, stream>>>(mid_t, Wb, outb, out, stats);
    k_bn2<<<13824, 256, 0, stream>>>(out, stats, ogam, obet);
}

// Round 3
// 478.449 us; speedup vs baseline: 1.5498x; 1.0114x over previous
//
#include <hip/hip_runtime.h>
#include <hip/hip_bf16.h>

#define C 48
#define C4 192
#define HW 192
#define NPIX (HW * HW)          // 36864
#define BATCH 8
#define CNT (BATCH * NPIX)      // 294912 samples per channel for BN

// Workspace layout. Total ~85.6 MB.
#define APRE_OFF   0ull
#define G_OFF      14155776ull
#define STATS_OFF  14229504ull
#define M2_OFF     14229696ull
#define MIDT_BYTE  57213696ull
#define WB_BYTE    85525248ull

typedef __attribute__((ext_vector_type(8))) short short8;
typedef __attribute__((ext_vector_type(4))) float f32x4;

static __device__ __forceinline__ unsigned pkbf(float a, float b) {
    union { __hip_bfloat162 h; unsigned u; } t;
    t.h = __float22bfloat162_rn(make_float2(a, b));
    return t.u;                                   // low16 = bf16(a), high16 = bf16(b)
}
static __device__ __forceinline__ float lo2f(unsigned p) { return __uint_as_float(p << 16); }
static __device__ __forceinline__ float hi2f(unsigned p) { return __uint_as_float(p & 0xffff0000u); }
static __device__ __forceinline__ short f2bfs(float f) { return (short)(pkbf(f, f) & 0xffffu); }

// ---------------------------------------------------------------- k_gram_mfma
// G[s,b,c,d] = sum_n X0[b,c,n] * Xs[b,d,n] via bf16 hi/lo split MFMA (3 products).
// Block: 512-n chunk, all 48x192 outputs.
// Round-2 rewrite:
//  * LDS stride 72 -> 68 shorts (52224 B total): 3 blocks/CU instead of 2.
//    At 136 B row stride, b64 staging writes hit 4 accesses/bank (minimum)
//    and ds_read_b128 fragment reads hit 8/bank (minimum) -> conflict-free.
//  * hi/lo dword pairs combined into single uint2 (b64) stores.
//  * Software prefetch: sub k+1's 12 float4 loads issued right after the
//    write-barrier, consumed at next pack -> HBM latency hides under
//    ds_read+MFMA+barrier of sub k. Source select is compile-time (s=it/3).
__global__ __launch_bounds__(256, 3) void k_gram_mfma(
    const float* __restrict__ x0, const float* __restrict__ x1,
    const float* __restrict__ x2, const float* __restrict__ x3,
    float* __restrict__ G)
{
    __shared__ short hibuf[C4 * 68];
    __shared__ short lobuf[C4 * 68];
    int b = blockIdx.y;
    int n0 = blockIdx.x * 512;
    int tid = threadIdx.x;
    int wid = tid >> 6, lane = tid & 63, col = lane & 15, quad = lane >> 4;

    const float* x0b = x0 + (size_t)b * C * NPIX;
    const float* x1b = x1 + (size_t)b * C * NPIX;
    const float* x2b = x2 + (size_t)b * C * NPIX;
    const float* x3b = x3 + (size_t)b * C * NPIX;

    f32x4 acc[3][3];
#pragma unroll
    for (int mt = 0; mt < 3; ++mt)
#pragma unroll
        for (int nt = 0; nt < 3; ++nt)
            acc[mt][nt] = (f32x4){0.f, 0.f, 0.f, 0.f};

    int scr = tid >> 4;            // 0..15: ch sub-row
    int n4 = (tid & 15) * 4;       // n offset within 64

    // Per-it source row: ch = scr + it*16 spans one source block since 16|48.
    //   s = it/3 (compile-time), c = scr + (it%3)*16.
    float4 pre[12];
#pragma unroll
    for (int it = 0; it < 12; ++it) {
        const float* xb = (it / 3 == 0) ? x0b : (it / 3 == 1) ? x1b
                        : (it / 3 == 2) ? x2b : x3b;
        pre[it] = *(const float4*)(xb + (size_t)(scr + (it % 3) * 16) * NPIX + n0 + n4);
    }

    for (int sub = 0; sub < 8; ++sub) {
        // pack prefetched tile -> LDS (hi/lo split), b64 stores
#pragma unroll
        for (int it = 0; it < 12; ++it) {
            int ch = scr + it * 16;
            float4 v = pre[it];
            unsigned h01 = pkbf(v.x, v.y), h23 = pkbf(v.z, v.w);
            float r0 = v.x - lo2f(h01), r1 = v.y - hi2f(h01);
            float r2 = v.z - lo2f(h23), r3 = v.w - hi2f(h23);
            unsigned l01 = pkbf(r0, r1), l23 = pkbf(r2, r3);
            *(uint2*)&hibuf[ch * 68 + n4] = make_uint2(h01, h23);
            *(uint2*)&lobuf[ch * 68 + n4] = make_uint2(l01, l23);
        }
        __syncthreads();

        // issue next sub's loads now; consumed after the trailing barrier
        if (sub < 7) {
            int nb = n0 + (sub + 1) * 64;
#pragma unroll
            for (int it = 0; it < 12; ++it) {
                const float* xb = (it / 3 == 0) ? x0b : (it / 3 == 1) ? x1b
                                : (it / 3 == 2) ? x2b : x3b;
                pre[it] = *(const float4*)(xb + (size_t)(scr + (it % 3) * 16) * NPIX + nb + n4);
            }
        }

#pragma unroll
        for (int kb = 0; kb < 2; ++kb) {
            int ko = kb * 32 + quad * 8;
            short8 ah[3], al[3], bh[3], bl[3];
#pragma unroll
            for (int mt = 0; mt < 3; ++mt) {
                ah[mt] = *(const short8*)&hibuf[(mt * 16 + col) * 68 + ko];
                al[mt] = *(const short8*)&lobuf[(mt * 16 + col) * 68 + ko];
            }
#pragma unroll
            for (int nt = 0; nt < 3; ++nt) {
                int row = (wid * 3 + nt) * 16 + col;
                bh[nt] = *(const short8*)&hibuf[row * 68 + ko];
                bl[nt] = *(const short8*)&lobuf[row * 68 + ko];
            }
#pragma unroll
            for (int mt = 0; mt < 3; ++mt)
#pragma unroll
                for (int nt = 0; nt < 3; ++nt) {
                    acc[mt][nt] = __builtin_amdgcn_mfma_f32_16x16x32_bf16(
                        ah[mt], bh[nt], acc[mt][nt], 0, 0, 0);
                    acc[mt][nt] = __builtin_amdgcn_mfma_f32_16x16x32_bf16(
                        ah[mt], bl[nt], acc[mt][nt], 0, 0, 0);
                    acc[mt][nt] = __builtin_amdgcn_mfma_f32_16x16x32_bf16(
                        al[mt], bh[nt], acc[mt][nt], 0, 0, 0);
                }
        }
        __syncthreads();
    }
#pragma unroll
    for (int mt = 0; mt < 3; ++mt)
#pragma unroll
        for (int nt = 0; nt < 3; ++nt) {
            int g = (wid * 3 + nt) * 16 + col;        // 0..191 = s*48 + d
            int s = g / C, d = g - s * C;
#pragma unroll
            for (int j = 0; j < 4; ++j) {
                int c = mt * 16 + quad * 4 + j;
                atomicAdd(&G[(((size_t)s * BATCH + b) * C + c) * C + d],
                          acc[mt][nt][j]);
            }
        }
}

// ---------------------------------------------------------------- k_small
__global__ __launch_bounds__(256) void k_small(
    const float* __restrict__ G,
    const float* __restrict__ Wa, const float* __restrict__ Wb,
    const float* __restrict__ Wc, const float* __restrict__ Wd,
    const float* __restrict__ fuse_w, float* __restrict__ M2g)
{
    int s = blockIdx.x, b = blockIdx.y;
    const float* Ws = (s == 0) ? Wa : (s == 1) ? Wb : (s == 2) ? Wc : Wd;

    __shared__ float g[C * C], wsm[C * C], wam[C * C], fw[C * C];
    __shared__ float t[C * C], e[C * C], m[C * C];
    int tid = threadIdx.x;

    const float* Gb = G + ((size_t)s * BATCH + b) * C * C;
    for (int k = tid; k < C * C; k += 256) {
        g[k] = Gb[k];
        wsm[k] = Ws[k];
        wam[k] = Wa[k];
        int o = k / C, c = k % C;
        fw[k] = fuse_w[(size_t)o * C4 + s * C + c];
    }
    __syncthreads();

    for (int k = tid; k < C * C; k += 256) {
        int c = k / C, d = k % C;
        float a = 0.f;
        for (int q = 0; q < C; ++q) a += g[c * C + q] * wsm[d * C + q];
        t[k] = a;
    }
    __syncthreads();
    for (int k = tid; k < C * C; k += 256) {
        int c = k / C, d = k % C;
        float a = 0.f;
        for (int q = 0; q < C; ++q) a += wam[c * C + q] * t[q * C + d];
        e[k] = a;
    }
    __syncthreads();
    if (tid < C) {
        int c = tid;
        float mn = e[c * C];
        for (int d = 1; d < C; ++d) mn = fminf(mn, e[c * C + d]);
        float sum = 0.f;
        for (int d = 0; d < C; ++d) {
            float v = __expf(mn - e[c * C + d]);
            e[c * C + d] = v;
            sum += v;
        }
        float inv = 1.0f / sum;
        for (int d = 0; d < C; ++d) e[c * C + d] *= inv;
    }
    __syncthreads();
    for (int k = tid; k < C * C; k += 256) {
        int d = k / C, o = k % C;
        float a = 0.f;
        for (int q = 0; q < C; ++q) a += fw[o * C + q] * e[q * C + d];
        m[k] = a;
    }
    __syncthreads();
    float* out = M2g + ((size_t)b * 4 + s) * C * C;
    for (int k = tid; k < C * C; k += 256) {
        int c = k / C, o = k % C;
        float a = 0.f;
        for (int q = 0; q < C; ++q) a += wsm[q * C + c] * m[q * C + o];
        out[k] = a;
    }
}

// ---------------------------------------------------------------- k_apply_mfma
// apre[b,o,n] = sum_{k=0..191} M2[b][k][o] * X[k][n] + fuse_b[o]  via MFMA.
//  * X tiles (64 n x 192 ch) staged in LDS via coalesced float4 loads
//    (2 adjacent channels x 4 pixels per thread -> channel-pair-packed dwords,
//    transposed [n][ch] rows). No more 8x scalar stride-NPIX gathers.
//  * Row stride 512 B + within-row XOR swizzle f=((row>>1)^(row>>2))&7 applied
//    as x ^= f<<4: both ds_write_b32 (2-way) and ds_read_b128 (8 acc/bank) hit
//    the wave64 bank-conflict minimum; bijective, in-bounds by construction.
//  * Compact K=192 (6 kq, channel runs may cross source boundaries inside LDS)
//    -> 18 MFMA per 16-n slice instead of 24 (no zero padding).
//  * Chunk 256 n -> grid 144x8 = 1152 blocks: 4.5 blocks/CU.
//  * BN stats: block-level LDS reduction, then 96 global atomics per block.
static __device__ __forceinline__ unsigned ladr(unsigned row, unsigned x) {
    unsigned f = ((row >> 1) ^ (row >> 2)) & 7;
    return (row << 9) | (x ^ (f << 4));
}

__global__ __launch_bounds__(256) void k_apply_mfma(
    const float* __restrict__ x0, const float* __restrict__ x1,
    const float* __restrict__ x2, const float* __restrict__ x3,
    const float* __restrict__ M2g, const float* __restrict__ fuse_b,
    float* __restrict__ apre, float* __restrict__ stats)
{
    __shared__ __align__(16) char xbuf[64 * 512];  // A-phase: [48 o][k192]; tiles: [64 n][192 ch]
    __shared__ float sst[96];
    char* lb = xbuf;

    int b = blockIdx.y;
    int n0 = blockIdx.x * 256;
    int tid = threadIdx.x;
    int wid = tid >> 6, lane = tid & 63, col = lane & 15, quad = lane >> 4;

    const float* x0b = x0 + (size_t)b * C * NPIX;
    const float* x1b = x1 + (size_t)b * C * NPIX;
    const float* x2b = x2 + (size_t)b * C * NPIX;
    const float* x3b = x3 + (size_t)b * C * NPIX;

    if (tid < 96) sst[tid] = 0.f;

    // ---- A = M2 (k = s*48+c compact, rows = o) into LDS as bf16
    const float* Mb = M2g + (size_t)b * 4 * C * C;
    for (int e = tid; e < 48 * 192; e += 256) {
        int k = e / 48, o = e - k * 48;            // consecutive lanes -> consecutive o (coalesced)
        *(short*)(lb + ladr(o, k * 2)) = f2bfs(Mb[(size_t)k * 48 + o]);
    }
    __syncthreads();

    short8 afr[3][6];
#pragma unroll
    for (int mt = 0; mt < 3; ++mt)
#pragma unroll
        for (int kq = 0; kq < 6; ++kq)
            afr[mt][kq] = *(const short8*)(lb + ladr(mt * 16 + col, kq * 64 + quad * 16));

    float fbv[3][4];
#pragma unroll
    for (int mt = 0; mt < 3; ++mt)
#pragma unroll
        for (int j = 0; j < 4; ++j)
            fbv[mt][j] = fuse_b[mt * 16 + quad * 4 + j];

    float s1[3][4] = {}, s2[3][4] = {};
    int nl = (wid << 4) + col;

    for (int sub = 0; sub < 4; ++sub) {
        int nb = n0 + sub * 64;
        __syncthreads();                            // prior tile's reads (or afr hoist) done
#pragma unroll
        for (int it = 0; it < 6; ++it) {
            int ef = tid + it * 256;                // 0..1535
            int p  = ef >> 4;                       // channel pair 0..95
            int nq = (ef & 15) << 2;                // 0..60
            int s  = p / 24;
            int c2 = (p - s * 24) * 2;
            const float* xp = ((s == 0) ? x0b : (s == 1) ? x1b : (s == 2) ? x2b : x3b)
                              + (size_t)c2 * NPIX + nb + nq;
            float4 va = *(const float4*)xp;         // channel c2,   n..n+3
            float4 vb = *(const float4*)(xp + NPIX);// channel c2+1, n..n+3
            unsigned p4 = (unsigned)p * 4;
            *(unsigned*)(lb + ladr(nq + 0, p4)) = pkbf(va.x, vb.x);
            *(unsigned*)(lb + ladr(nq + 1, p4)) = pkbf(va.y, vb.y);
            *(unsigned*)(lb + ladr(nq + 2, p4)) = pkbf(va.z, vb.z);
            *(unsigned*)(lb + ladr(nq + 3, p4)) = pkbf(va.w, vb.w);
        }
        __syncthreads();

        f32x4 acc[3];
        acc[0] = (f32x4){0.f, 0.f, 0.f, 0.f};
        acc[1] = (f32x4){0.f, 0.f, 0.f, 0.f};
        acc[2] = (f32x4){0.f, 0.f, 0.f, 0.f};
#pragma unroll
        for (int kq = 0; kq < 6; ++kq) {
            short8 bfr = *(const short8*)(lb + ladr(nl, kq * 64 + quad * 16));
            acc[0] = __builtin_amdgcn_mfma_f32_16x16x32_bf16(afr[0][kq], bfr, acc[0], 0, 0, 0);
            acc[1] = __builtin_amdgcn_mfma_f32_16x16x32_bf16(afr[1][kq], bfr, acc[1], 0, 0, 0);
            acc[2] = __builtin_amdgcn_mfma_f32_16x16x32_bf16(afr[2][kq], bfr, acc[2], 0, 0, 0);
        }

        int n = nb + nl;
#pragma unroll
        for (int mt = 0; mt < 3; ++mt)
#pragma unroll
            for (int j = 0; j < 4; ++j) {
                int o = mt * 16 + quad * 4 + j;
                float val = acc[mt][j] + fbv[mt][j];
                apre[((size_t)b * C + o) * NPIX + n] = val;
                s1[mt][j] += val;
                s2[mt][j] += val * val;
            }
    }

#pragma unroll
    for (int mt = 0; mt < 3; ++mt)
#pragma unroll
        for (int j = 0; j < 4; ++j) {
            float a = s1[mt][j], q = s2[mt][j];
#pragma unroll
            for (int off = 8; off; off >>= 1) {
                a += __shfl_down(a, off, 16);
                q += __shfl_down(q, off, 16);
            }
            if (col == 0) {
                int o = mt * 16 + quad * 4 + j;
                atomicAdd(&sst[o], a);
                atomicAdd(&sst[48 + o], q);
            }
        }
    __syncthreads();
    if (tid < 96) atomicAdd(&stats[tid], sst[tid]);   // stats[o], stats[C+o] are contiguous
}

// ---------------------------------------------------------------- k_bn1t
// mid_t[b,px,c] = bf16(gamma_cam*relu(BN(apre)) + input); LDS tile-transpose
// makes the global bf16 store a contiguous short4 stream.
__global__ __launch_bounds__(256) void k_bn1t(
    const float* __restrict__ apre, const float* __restrict__ inp,
    const float* __restrict__ stats, const float* __restrict__ gamma,
    const float* __restrict__ beta, const float* __restrict__ gcam,
    short* __restrict__ mid_t)
{
    __shared__ short t[64 * C];     // [px_local][c]
    int b = blockIdx.y;
    int n0 = blockIdx.x * 64;
    int tid = threadIdx.x;
    const float invc = 1.0f / (float)CNT;
    float g = gcam[0];

#pragma unroll
    for (int it = 0; it < 3; ++it) {
        int e = tid + it * 256;                 // 0..767 = 48 ch x 16 px-quads
        int c = e >> 4, pq = (e & 15) * 4;
        float mu = stats[c] * invc;
        float var = stats[C + c] * invc - mu * mu;
        float sc = gamma[c] * rsqrtf(var + 1e-5f);
        float be = beta[c] - mu * sc;
        size_t base = ((size_t)b * C + c) * NPIX + n0 + pq;
        float4 v = *(const float4*)(apre + base);
        float4 x = *(const float4*)(inp + base);
        t[(pq + 0) * C + c] = f2bfs(fmaxf(v.x * sc + be, 0.f) * g + x.x);
        t[(pq + 1) * C + c] = f2bfs(fmaxf(v.y * sc + be, 0.f) * g + x.y);
        t[(pq + 2) * C + c] = f2bfs(fmaxf(v.z * sc + be, 0.f) * g + x.z);
        t[(pq + 3) * C + c] = f2bfs(fmaxf(v.w * sc + be, 0.f) * g + x.w);
    }
    __syncthreads();
    short* mb = mid_t + ((size_t)b * NPIX + n0) * C;
#pragma unroll
    for (int it = 0; it < 3; ++it) {
        int e = tid + it * 256;                 // contiguous: row = 12 short4s
        *(short4*)(mb + e * 4) = *(const short4*)&t[e * 4];
    }
}

// ---------------------------------------------------------------- k_prep
__global__ __launch_bounds__(256) void k_prep(
    const float* __restrict__ outw, short* __restrict__ Wb)
{
    int idx = blockIdx.x * 256 + threadIdx.x;
    if (idx >= 9 * 48 * 64) return;
    int i = idx & 63;
    int o = (idx >> 6) % 48;
    int tap = idx / (64 * 48);
    float v = (i < C) ? outw[((size_t)o * C + i) * 9 + tap] : 0.f;
    Wb[idx] = f2bfs(v);
}

// ---------------------------------------------------------------- k_conv_mfma
__global__ __launch_bounds__(256) void k_conv_mfma(
    const short* __restrict__ mid_t, const short* __restrict__ Wb,
    const float* __restrict__ bias, float* __restrict__ out,
    float* __restrict__ stats)
{
    __shared__ short xl[324 * 72];
    __shared__ float sst[96];
    int b = blockIdx.y;
    int ty = blockIdx.x / 12, tx = blockIdx.x % 12;
    int h0 = ty * 16, w0 = tx * 16;
    int tid = threadIdx.x;

    if (tid < 96) sst[tid] = 0.f;

    for (int ch = tid; ch < 2916; ch += 256) {
        int lpx = ch / 9, part = ch % 9;
        int hh = h0 - 1 + lpx / 18, ww = w0 - 1 + lpx % 18;
        short8 v = {0, 0, 0, 0, 0, 0, 0, 0};
        if (part < 6 && hh >= 0 && hh < HW && ww >= 0 && ww < HW)
            v = *(const short8*)(mid_t + ((size_t)b * NPIX + hh * HW + ww) * C + part * 8);
        *(short8*)(xl + lpx * 72 + part * 8) = v;
    }
    __syncthreads();

    int wid = tid >> 6, lane = tid & 63;
    int col = lane & 15, quad = lane >> 4;

    f32x4 acc[3][4];
#pragma unroll
    for (int mt = 0; mt < 3; ++mt)
#pragma unroll
        for (int rr = 0; rr < 4; ++rr)
            acc[mt][rr] = (f32x4){0.f, 0.f, 0.f, 0.f};

#pragma unroll
    for (int tap = 0; tap < 9; ++tap) {
        int dh = tap / 3, dw = tap % 3;
#pragma unroll
        for (int kb = 0; kb < 2; ++kb) {
            short8 afr[3];
#pragma unroll
            for (int mt = 0; mt < 3; ++mt)
                afr[mt] = *(const short8*)(Wb + ((size_t)(tap * 48 + mt * 16 + col)) * 64
                                               + kb * 32 + quad * 8);
#pragma unroll
            for (int rr = 0; rr < 4; ++rr) {
                int r = wid * 4 + rr;
                int lpx = (r + dh) * 18 + col + dw;
                short8 bfr = *(const short8*)(xl + lpx * 72 + kb * 32 + quad * 8);
#pragma unroll
                for (int mt = 0; mt < 3; ++mt)
                    acc[mt][rr] = __builtin_amdgcn_mfma_f32_16x16x32_bf16(
                        afr[mt], bfr, acc[mt][rr], 0, 0, 0);
            }
        }
    }

    float s1[3][4] = {}, s2[3][4] = {};
#pragma unroll
    for (int mt = 0; mt < 3; ++mt)
#pragma unroll
        for (int rr = 0; rr < 4; ++rr) {
            int r = wid * 4 + rr;
            f32x4 v = acc[mt][rr];
#pragma unroll
            for (int j = 0; j < 4; ++j) {
                int o = mt * 16 + quad * 4 + j;
                float val = v[j] + bias[o];
                out[((size_t)b * C + o) * NPIX + (h0 + r) * HW + w0 + col] = val;
                s1[mt][j] += val;
                s2[mt][j] += val * val;
            }
        }
#pragma unroll
    for (int mt = 0; mt < 3; ++mt)
#pragma unroll
        for (int j = 0; j < 4; ++j) {
            float a = s1[mt][j], q = s2[mt][j];
#pragma unroll
            for (int off = 8; off; off >>= 1) {
                a += __shfl_down(a, off, 16);
                q += __shfl_down(q, off, 16);
            }
            if (col == 0) {
                int o = mt * 16 + quad * 4 + j;
                atomicAdd(&sst[o], a);
                atomicAdd(&sst[48 + o], q);
            }
        }
    __syncthreads();
    if (tid < 48)       atomicAdd(&stats[2 * C + tid], sst[tid]);
    else if (tid < 96)  atomicAdd(&stats[3 * C + tid - 48], sst[tid]);
}

// ---------------------------------------------------------------- k_bn2
__global__ __launch_bounds__(256) void k_bn2(
    float* __restrict__ out, const float* __restrict__ stats,
    const float* __restrict__ gamma, const float* __restrict__ beta)
{
    size_t i = ((size_t)blockIdx.x * 256 + threadIdx.x) * 4;
    int c = (int)((i / NPIX) % C);
    const float invc = 1.0f / (float)CNT;
    float mu = stats[2 * C + c] * invc;
    float var = stats[3 * C + c] * invc - mu * mu;
    float sc = gamma[c] * rsqrtf(var + 1e-5f);
    float be = beta[c] - mu * sc;

    float4 v = *(float4*)(out + i);
    v.x = fmaxf(v.x * sc + be, 0.f);
    v.y = fmaxf(v.y * sc + be, 0.f);
    v.z = fmaxf(v.z * sc + be, 0.f);
    v.w = fmaxf(v.w * sc + be, 0.f);
    *(float4*)(out + i) = v;
}

// ---------------------------------------------------------------- launch
extern "C" void kernel_launch(void* const* d_in, const int* in_sizes, int n_in,
                              void* d_out, int out_size, void* d_ws, size_t ws_size,
                              hipStream_t stream)
{
    const float* inp   = (const float*)d_in[0];
    const float* fb    = (const float*)d_in[1];
    const float* fc    = (const float*)d_in[2];
    const float* fd    = (const float*)d_in[3];
    const float* Wa    = (const float*)d_in[4];
    const float* Wbm   = (const float*)d_in[5];
    const float* Wcm   = (const float*)d_in[6];
    const float* Wdm   = (const float*)d_in[7];
    const float* fusew = (const float*)d_in[8];
    const float* fuseb = (const float*)d_in[9];
    const float* fgam  = (const float*)d_in[10];
    const float* fbet  = (const float*)d_in[11];
    const float* gcam  = (const float*)d_in[12];
    const float* outw  = (const float*)d_in[13];
    const float* outb  = (const float*)d_in[14];
    const float* ogam  = (const float*)d_in[15];
    const float* obet  = (const float*)d_in[16];

    float* ws    = (float*)d_ws;
    float* apre  = ws + APRE_OFF;
    float* G     = ws + G_OFF;
    float* stats = ws + STATS_OFF;
    float* M2g   = ws + M2_OFF;
    short* mid_t = (short*)((char*)d_ws + MIDT_BYTE);
    short* Wb    = (short*)((char*)d_ws + WB_BYTE);
    float* out   = (float*)d_out;

    hipMemsetAsync(G, 0, (73728ull + 192ull) * sizeof(float), stream);

    k_prep<<<108, 256, 0, stream>>>(outw, Wb);
    k_gram_mfma<<<dim3(72, BATCH), 256, 0, stream>>>(inp, fb, fc, fd, G);
    k_small<<<dim3(4, BATCH), 256, 0, stream>>>(G, Wa, Wbm, Wcm, Wdm, fusew, M2g);
    k_apply_mfma<<<dim3(144, BATCH), 256, 0, stream>>>(inp, fb, fc, fd, M2g, fuseb, apre, stats);
    k_bn1t<<<dim3(576, BATCH), 256, 0, stream>>>(apre, inp, stats, fgam, fbet, gcam, mid_t);
    k_conv_mfma<<<dim3(144, BATCH), 256, 0, stream>>>(mid_t, Wb, outb, out, stats);
    k_bn2<<<13824, 256, 0, stream>>>(out, stats, ogam, obet);
}

// Round 4
// 476.225 us; speedup vs baseline: 1.5570x; 1.0047x over previous
//
#include <hip/hip_runtime.h>
#include <hip/hip_bf16.h>

#define C 48
#define C4 192
#define HW 192
#define NPIX (HW * HW)          // 36864
#define BATCH 8
#define CNT (BATCH * NPIX)      // 294912 samples per channel for BN

// Workspace layout. Total ~85.6 MB.
#define APRE_OFF   0ull
#define G_OFF      14155776ull
#define STATS_OFF  14229504ull
#define M2_OFF     14229696ull
#define MIDT_BYTE  57213696ull
#define WB_BYTE    85525248ull

typedef __attribute__((ext_vector_type(8))) short short8;
typedef __attribute__((ext_vector_type(4))) float f32x4;

static __device__ __forceinline__ unsigned pkbf(float a, float b) {
    union { __hip_bfloat162 h; unsigned u; } t;
    t.h = __float22bfloat162_rn(make_float2(a, b));
    return t.u;                                   // low16 = bf16(a), high16 = bf16(b)
}
static __device__ __forceinline__ float lo2f(unsigned p) { return __uint_as_float(p << 16); }
static __device__ __forceinline__ float hi2f(unsigned p) { return __uint_as_float(p & 0xffff0000u); }
static __device__ __forceinline__ short f2bfs(float f) { return (short)(pkbf(f, f) & 0xffffu); }

// ---------------------------------------------------------------- k_gram_mfma
// G[s,b,c,d] = sum_n X0[b,c,n] * Xs[b,d,n] via bf16 hi/lo split MFMA (3 products).
// Round-3: n-chunk 512 -> 256 (grid 144x8 = 1152 blocks). Round-3 post-mortem
// showed the 576-block grid (2.25 blocks/CU) was the occupancy cap, not LDS:
// every pipe <15% busy, 6 resident waves/CU. 1152 blocks hits the 3-block/CU
// LDS ceiling (52224 B) -> ~12 waves/CU. Cost: 2x G atomics (block-end,
// staggered). Per-sub structure unchanged: stride-68 conflict-free layout,
// b64 stores, software prefetch, hi/lo 3-product MFMA.
__global__ __launch_bounds__(256, 3) void k_gram_mfma(
    const float* __restrict__ x0, const float* __restrict__ x1,
    const float* __restrict__ x2, const float* __restrict__ x3,
    float* __restrict__ G)
{
    __shared__ short hibuf[C4 * 68];
    __shared__ short lobuf[C4 * 68];
    int b = blockIdx.y;
    int n0 = blockIdx.x * 256;
    int tid = threadIdx.x;
    int wid = tid >> 6, lane = tid & 63, col = lane & 15, quad = lane >> 4;

    const float* x0b = x0 + (size_t)b * C * NPIX;
    const float* x1b = x1 + (size_t)b * C * NPIX;
    const float* x2b = x2 + (size_t)b * C * NPIX;
    const float* x3b = x3 + (size_t)b * C * NPIX;

    f32x4 acc[3][3];
#pragma unroll
    for (int mt = 0; mt < 3; ++mt)
#pragma unroll
        for (int nt = 0; nt < 3; ++nt)
            acc[mt][nt] = (f32x4){0.f, 0.f, 0.f, 0.f};

    int scr = tid >> 4;            // 0..15: ch sub-row
    int n4 = (tid & 15) * 4;       // n offset within 64

    // Per-it source row: ch = scr + it*16 spans one source block since 16|48.
    //   s = it/3 (compile-time), c = scr + (it%3)*16.
    float4 pre[12];
#pragma unroll
    for (int it = 0; it < 12; ++it) {
        const float* xb = (it / 3 == 0) ? x0b : (it / 3 == 1) ? x1b
                        : (it / 3 == 2) ? x2b : x3b;
        pre[it] = *(const float4*)(xb + (size_t)(scr + (it % 3) * 16) * NPIX + n0 + n4);
    }

    for (int sub = 0; sub < 4; ++sub) {
        // pack prefetched tile -> LDS (hi/lo split), b64 stores
#pragma unroll
        for (int it = 0; it < 12; ++it) {
            int ch = scr + it * 16;
            float4 v = pre[it];
            unsigned h01 = pkbf(v.x, v.y), h23 = pkbf(v.z, v.w);
            float r0 = v.x - lo2f(h01), r1 = v.y - hi2f(h01);
            float r2 = v.z - lo2f(h23), r3 = v.w - hi2f(h23);
            unsigned l01 = pkbf(r0, r1), l23 = pkbf(r2, r3);
            *(uint2*)&hibuf[ch * 68 + n4] = make_uint2(h01, h23);
            *(uint2*)&lobuf[ch * 68 + n4] = make_uint2(l01, l23);
        }
        __syncthreads();

        // issue next sub's loads now; consumed after the trailing barrier
        if (sub < 3) {
            int nb = n0 + (sub + 1) * 64;
#pragma unroll
            for (int it = 0; it < 12; ++it) {
                const float* xb = (it / 3 == 0) ? x0b : (it / 3 == 1) ? x1b
                                : (it / 3 == 2) ? x2b : x3b;
                pre[it] = *(const float4*)(xb + (size_t)(scr + (it % 3) * 16) * NPIX + nb + n4);
            }
        }

#pragma unroll
        for (int kb = 0; kb < 2; ++kb) {
            int ko = kb * 32 + quad * 8;
            short8 ah[3], al[3], bh[3], bl[3];
#pragma unroll
            for (int mt = 0; mt < 3; ++mt) {
                ah[mt] = *(const short8*)&hibuf[(mt * 16 + col) * 68 + ko];
                al[mt] = *(const short8*)&lobuf[(mt * 16 + col) * 68 + ko];
            }
#pragma unroll
            for (int nt = 0; nt < 3; ++nt) {
                int row = (wid * 3 + nt) * 16 + col;
                bh[nt] = *(const short8*)&hibuf[row * 68 + ko];
                bl[nt] = *(const short8*)&lobuf[row * 68 + ko];
            }
#pragma unroll
            for (int mt = 0; mt < 3; ++mt)
#pragma unroll
                for (int nt = 0; nt < 3; ++nt) {
                    acc[mt][nt] = __builtin_amdgcn_mfma_f32_16x16x32_bf16(
                        ah[mt], bh[nt], acc[mt][nt], 0, 0, 0);
                    acc[mt][nt] = __builtin_amdgcn_mfma_f32_16x16x32_bf16(
                        ah[mt], bl[nt], acc[mt][nt], 0, 0, 0);
                    acc[mt][nt] = __builtin_amdgcn_mfma_f32_16x16x32_bf16(
                        al[mt], bh[nt], acc[mt][nt], 0, 0, 0);
                }
        }
        __syncthreads();
    }
#pragma unroll
    for (int mt = 0; mt < 3; ++mt)
#pragma unroll
        for (int nt = 0; nt < 3; ++nt) {
            int g = (wid * 3 + nt) * 16 + col;        // 0..191 = s*48 + d
            int s = g / C, d = g - s * C;
#pragma unroll
            for (int j = 0; j < 4; ++j) {
                int c = mt * 16 + quad * 4 + j;
                atomicAdd(&G[(((size_t)s * BATCH + b) * C + c) * C + d],
                          acc[mt][nt][j]);
            }
        }
}

// ---------------------------------------------------------------- k_small
__global__ __launch_bounds__(256) void k_small(
    const float* __restrict__ G,
    const float* __restrict__ Wa, const float* __restrict__ Wb,
    const float* __restrict__ Wc, const float* __restrict__ Wd,
    const float* __restrict__ fuse_w, float* __restrict__ M2g)
{
    int s = blockIdx.x, b = blockIdx.y;
    const float* Ws = (s == 0) ? Wa : (s == 1) ? Wb : (s == 2) ? Wc : Wd;

    __shared__ float g[C * C], wsm[C * C], wam[C * C], fw[C * C];
    __shared__ float t[C * C], e[C * C], m[C * C];
    int tid = threadIdx.x;

    const float* Gb = G + ((size_t)s * BATCH + b) * C * C;
    for (int k = tid; k < C * C; k += 256) {
        g[k] = Gb[k];
        wsm[k] = Ws[k];
        wam[k] = Wa[k];
        int o = k / C, c = k % C;
        fw[k] = fuse_w[(size_t)o * C4 + s * C + c];
    }
    __syncthreads();

    for (int k = tid; k < C * C; k += 256) {
        int c = k / C, d = k % C;
        float a = 0.f;
        for (int q = 0; q < C; ++q) a += g[c * C + q] * wsm[d * C + q];
        t[k] = a;
    }
    __syncthreads();
    for (int k = tid; k < C * C; k += 256) {
        int c = k / C, d = k % C;
        float a = 0.f;
        for (int q = 0; q < C; ++q) a += wam[c * C + q] * t[q * C + d];
        e[k] = a;
    }
    __syncthreads();
    if (tid < C) {
        int c = tid;
        float mn = e[c * C];
        for (int d = 1; d < C; ++d) mn = fminf(mn, e[c * C + d]);
        float sum = 0.f;
        for (int d = 0; d < C; ++d) {
            float v = __expf(mn - e[c * C + d]);
            e[c * C + d] = v;
            sum += v;
        }
        float inv = 1.0f / sum;
        for (int d = 0; d < C; ++d) e[c * C + d] *= inv;
    }
    __syncthreads();
    for (int k = tid; k < C * C; k += 256) {
        int d = k / C, o = k % C;
        float a = 0.f;
        for (int q = 0; q < C; ++q) a += fw[o * C + q] * e[q * C + d];
        m[k] = a;
    }
    __syncthreads();
    float* out = M2g + ((size_t)b * 4 + s) * C * C;
    for (int k = tid; k < C * C; k += 256) {
        int c = k / C, o = k % C;
        float a = 0.f;
        for (int q = 0; q < C; ++q) a += wsm[q * C + c] * m[q * C + o];
        out[k] = a;
    }
}

// ---------------------------------------------------------------- k_apply_mfma
// apre[b,o,n] = sum_{k=0..191} M2[b][k][o] * X[k][n] + fuse_b[o]  via MFMA.
//  * X tiles (64 n x 192 ch) staged in LDS via coalesced float4 loads
//    (2 adjacent channels x 4 pixels per thread -> channel-pair-packed dwords,
//    transposed [n][ch] rows). No more 8x scalar stride-NPIX gathers.
//  * Row stride 512 B + within-row XOR swizzle f=((row>>1)^(row>>2))&7 applied
//    as x ^= f<<4: both ds_write_b32 (2-way) and ds_read_b128 (8 acc/bank) hit
//    the wave64 bank-conflict minimum; bijective, in-bounds by construction.
//  * Compact K=192 (6 kq, channel runs may cross source boundaries inside LDS)
//    -> 18 MFMA per 16-n slice instead of 24 (no zero padding).
//  * Chunk 256 n -> grid 144x8 = 1152 blocks: 4.5 blocks/CU.
//  * BN stats: block-level LDS reduction, then 96 global atomics per block.
static __device__ __forceinline__ unsigned ladr(unsigned row, unsigned x) {
    unsigned f = ((row >> 1) ^ (row >> 2)) & 7;
    return (row << 9) | (x ^ (f << 4));
}

__global__ __launch_bounds__(256) void k_apply_mfma(
    const float* __restrict__ x0, const float* __restrict__ x1,
    const float* __restrict__ x2, const float* __restrict__ x3,
    const float* __restrict__ M2g, const float* __restrict__ fuse_b,
    float* __restrict__ apre, float* __restrict__ stats)
{
    __shared__ __align__(16) char xbuf[64 * 512];  // A-phase: [48 o][k192]; tiles: [64 n][192 ch]
    __shared__ float sst[96];
    char* lb = xbuf;

    int b = blockIdx.y;
    int n0 = blockIdx.x * 256;
    int tid = threadIdx.x;
    int wid = tid >> 6, lane = tid & 63, col = lane & 15, quad = lane >> 4;

    const float* x0b = x0 + (size_t)b * C * NPIX;
    const float* x1b = x1 + (size_t)b * C * NPIX;
    const float* x2b = x2 + (size_t)b * C * NPIX;
    const float* x3b = x3 + (size_t)b * C * NPIX;

    if (tid < 96) sst[tid] = 0.f;

    // ---- A = M2 (k = s*48+c compact, rows = o) into LDS as bf16
    const float* Mb = M2g + (size_t)b * 4 * C * C;
    for (int e = tid; e < 48 * 192; e += 256) {
        int k = e / 48, o = e - k * 48;            // consecutive lanes -> consecutive o (coalesced)
        *(short*)(lb + ladr(o, k * 2)) = f2bfs(Mb[(size_t)k * 48 + o]);
    }
    __syncthreads();

    short8 afr[3][6];
#pragma unroll
    for (int mt = 0; mt < 3; ++mt)
#pragma unroll
        for (int kq = 0; kq < 6; ++kq)
            afr[mt][kq] = *(const short8*)(lb + ladr(mt * 16 + col, kq * 64 + quad * 16));

    float fbv[3][4];
#pragma unroll
    for (int mt = 0; mt < 3; ++mt)
#pragma unroll
        for (int j = 0; j < 4; ++j)
            fbv[mt][j] = fuse_b[mt * 16 + quad * 4 + j];

    float s1[3][4] = {}, s2[3][4] = {};
    int nl = (wid << 4) + col;

    for (int sub = 0; sub < 4; ++sub) {
        int nb = n0 + sub * 64;
        __syncthreads();                            // prior tile's reads (or afr hoist) done
#pragma unroll
        for (int it = 0; it < 6; ++it) {
            int ef = tid + it * 256;                // 0..1535
            int p  = ef >> 4;                       // channel pair 0..95
            int nq = (ef & 15) << 2;                // 0..60
            int s  = p / 24;
            int c2 = (p - s * 24) * 2;
            const float* xp = ((s == 0) ? x0b : (s == 1) ? x1b : (s == 2) ? x2b : x3b)
                              + (size_t)c2 * NPIX + nb + nq;
            float4 va = *(const float4*)xp;         // channel c2,   n..n+3
            float4 vb = *(const float4*)(xp + NPIX);// channel c2+1, n..n+3
            unsigned p4 = (unsigned)p * 4;
            *(unsigned*)(lb + ladr(nq + 0, p4)) = pkbf(va.x, vb.x);
            *(unsigned*)(lb + ladr(nq + 1, p4)) = pkbf(va.y, vb.y);
            *(unsigned*)(lb + ladr(nq + 2, p4)) = pkbf(va.z, vb.z);
            *(unsigned*)(lb + ladr(nq + 3, p4)) = pkbf(va.w, vb.w);
        }
        __syncthreads();

        f32x4 acc[3];
        acc[0] = (f32x4){0.f, 0.f, 0.f, 0.f};
        acc[1] = (f32x4){0.f, 0.f, 0.f, 0.f};
        acc[2] = (f32x4){0.f, 0.f, 0.f, 0.f};
#pragma unroll
        for (int kq = 0; kq < 6; ++kq) {
            short8 bfr = *(const short8*)(lb + ladr(nl, kq * 64 + quad * 16));
            acc[0] = __builtin_amdgcn_mfma_f32_16x16x32_bf16(afr[0][kq], bfr, acc[0], 0, 0, 0);
            acc[1] = __builtin_amdgcn_mfma_f32_16x16x32_bf16(afr[1][kq], bfr, acc[1], 0, 0, 0);
            acc[2] = __builtin_amdgcn_mfma_f32_16x16x32_bf16(afr[2][kq], bfr, acc[2], 0, 0, 0);
        }

        int n = nb + nl;
#pragma unroll
        for (int mt = 0; mt < 3; ++mt)
#pragma unroll
            for (int j = 0; j < 4; ++j) {
                int o = mt * 16 + quad * 4 + j;
                float val = acc[mt][j] + fbv[mt][j];
                apre[((size_t)b * C + o) * NPIX + n] = val;
                s1[mt][j] += val;
                s2[mt][j] += val * val;
            }
    }

#pragma unroll
    for (int mt = 0; mt < 3; ++mt)
#pragma unroll
        for (int j = 0; j < 4; ++j) {
            float a = s1[mt][j], q = s2[mt][j];
#pragma unroll
            for (int off = 8; off; off >>= 1) {
                a += __shfl_down(a, off, 16);
                q += __shfl_down(q, off, 16);
            }
            if (col == 0) {
                int o = mt * 16 + quad * 4 + j;
                atomicAdd(&sst[o], a);
                atomicAdd(&sst[48 + o], q);
            }
        }
    __syncthreads();
    if (tid < 96) atomicAdd(&stats[tid], sst[tid]);   // stats[o], stats[C+o] are contiguous
}

// ---------------------------------------------------------------- k_bn1t
// mid_t[b,px,c] = bf16(gamma_cam*relu(BN(apre)) + input); LDS tile-transpose
// makes the global bf16 store a contiguous short4 stream.
__global__ __launch_bounds__(256) void k_bn1t(
    const float* __restrict__ apre, const float* __restrict__ inp,
    const float* __restrict__ stats, const float* __restrict__ gamma,
    const float* __restrict__ beta, const float* __restrict__ gcam,
    short* __restrict__ mid_t)
{
    __shared__ short t[64 * C];     // [px_local][c]
    int b = blockIdx.y;
    int n0 = blockIdx.x * 64;
    int tid = threadIdx.x;
    const float invc = 1.0f / (float)CNT;
    float g = gcam[0];

#pragma unroll
    for (int it = 0; it < 3; ++it) {
        int e = tid + it * 256;                 // 0..767 = 48 ch x 16 px-quads
        int c = e >> 4, pq = (e & 15) * 4;
        float mu = stats[c] * invc;
        float var = stats[C + c] * invc - mu * mu;
        float sc = gamma[c] * rsqrtf(var + 1e-5f);
        float be = beta[c] - mu * sc;
        size_t base = ((size_t)b * C + c) * NPIX + n0 + pq;
        float4 v = *(const float4*)(apre + base);
        float4 x = *(const float4*)(inp + base);
        t[(pq + 0) * C + c] = f2bfs(fmaxf(v.x * sc + be, 0.f) * g + x.x);
        t[(pq + 1) * C + c] = f2bfs(fmaxf(v.y * sc + be, 0.f) * g + x.y);
        t[(pq + 2) * C + c] = f2bfs(fmaxf(v.z * sc + be, 0.f) * g + x.z);
        t[(pq + 3) * C + c] = f2bfs(fmaxf(v.w * sc + be, 0.f) * g + x.w);
    }
    __syncthreads();
    short* mb = mid_t + ((size_t)b * NPIX + n0) * C;
#pragma unroll
    for (int it = 0; it < 3; ++it) {
        int e = tid + it * 256;                 // contiguous: row = 12 short4s
        *(short4*)(mb + e * 4) = *(const short4*)&t[e * 4];
    }
}

// ---------------------------------------------------------------- k_prep
__global__ __launch_bounds__(256) void k_prep(
    const float* __restrict__ outw, short* __restrict__ Wb)
{
    int idx = blockIdx.x * 256 + threadIdx.x;
    if (idx >= 9 * 48 * 64) return;
    int i = idx & 63;
    int o = (idx >> 6) % 48;
    int tap = idx / (64 * 48);
    float v = (i < C) ? outw[((size_t)o * C + i) * 9 + tap] : 0.f;
    Wb[idx] = f2bfs(v);
}

// ---------------------------------------------------------------- k_conv_mfma
__global__ __launch_bounds__(256) void k_conv_mfma(
    const short* __restrict__ mid_t, const short* __restrict__ Wb,
    const float* __restrict__ bias, float* __restrict__ out,
    float* __restrict__ stats)
{
    __shared__ short xl[324 * 72];
    __shared__ float sst[96];
    int b = blockIdx.y;
    int ty = blockIdx.x / 12, tx = blockIdx.x % 12;
    int h0 = ty * 16, w0 = tx * 16;
    int tid = threadIdx.x;

    if (tid < 96) sst[tid] = 0.f;

    for (int ch = tid; ch < 2916; ch += 256) {
        int lpx = ch / 9, part = ch % 9;
        int hh = h0 - 1 + lpx / 18, ww = w0 - 1 + lpx % 18;
        short8 v = {0, 0, 0, 0, 0, 0, 0, 0};
        if (part < 6 && hh >= 0 && hh < HW && ww >= 0 && ww < HW)
            v = *(const short8*)(mid_t + ((size_t)b * NPIX + hh * HW + ww) * C + part * 8);
        *(short8*)(xl + lpx * 72 + part * 8) = v;
    }
    __syncthreads();

    int wid = tid >> 6, lane = tid & 63;
    int col = lane & 15, quad = lane >> 4;

    f32x4 acc[3][4];
#pragma unroll
    for (int mt = 0; mt < 3; ++mt)
#pragma unroll
        for (int rr = 0; rr < 4; ++rr)
            acc[mt][rr] = (f32x4){0.f, 0.f, 0.f, 0.f};

#pragma unroll
    for (int tap = 0; tap < 9; ++tap) {
        int dh = tap / 3, dw = tap % 3;
#pragma unroll
        for (int kb = 0; kb < 2; ++kb) {
            short8 afr[3];
#pragma unroll
            for (int mt = 0; mt < 3; ++mt)
                afr[mt] = *(const short8*)(Wb + ((size_t)(tap * 48 + mt * 16 + col)) * 64
                                               + kb * 32 + quad * 8);
#pragma unroll
            for (int rr = 0; rr < 4; ++rr) {
                int r = wid * 4 + rr;
                int lpx = (r + dh) * 18 + col + dw;
                short8 bfr = *(const short8*)(xl + lpx * 72 + kb * 32 + quad * 8);
#pragma unroll
                for (int mt = 0; mt < 3; ++mt)
                    acc[mt][rr] = __builtin_amdgcn_mfma_f32_16x16x32_bf16(
                        afr[mt], bfr, acc[mt][rr], 0, 0, 0);
            }
        }
    }

    float s1[3][4] = {}, s2[3][4] = {};
#pragma unroll
    for (int mt = 0; mt < 3; ++mt)
#pragma unroll
        for (int rr = 0; rr < 4; ++rr) {
            int r = wid * 4 + rr;
            f32x4 v = acc[mt][rr];
#pragma unroll
            for (int j = 0; j < 4; ++j) {
                int o = mt * 16 + quad * 4 + j;
                float val = v[j] + bias[o];
                out[((size_t)b * C + o) * NPIX + (h0 + r) * HW + w0 + col] = val;
                s1[mt][j] += val;
                s2[mt][j] += val * val;
            }
        }
#pragma unroll
    for (int mt = 0; mt < 3; ++mt)
#pragma unroll
        for (int j = 0; j < 4; ++j) {
            float a = s1[mt][j], q = s2[mt][j];
#pragma unroll
            for (int off = 8; off; off >>= 1) {
                a += __shfl_down(a, off, 16);
                q += __shfl_down(q, off, 16);
            }
            if (col == 0) {
                int o = mt * 16 + quad * 4 + j;
                atomicAdd(&sst[o], a);
                atomicAdd(&sst[48 + o], q);
            }
        }
    __syncthreads();
    if (tid < 48)       atomicAdd(&stats[2 * C + tid], sst[tid]);
    else if (tid < 96)  atomicAdd(&stats[3 * C + tid - 48], sst[tid]);
}

// ---------------------------------------------------------------- k_bn2
__global__ __launch_bounds__(256) void k_bn2(
    float* __restrict__ out, const float* __restrict__ stats,
    const float* __restrict__ gamma, const float* __restrict__ beta)
{
    size_t i = ((size_t)blockIdx.x * 256 + threadIdx.x) * 4;
    int c = (int)((i / NPIX) % C);
    const float invc = 1.0f / (float)CNT;
    float mu = stats[2 * C + c] * invc;
    float var = stats[3 * C + c] * invc - mu * mu;
    float sc = gamma[c] * rsqrtf(var + 1e-5f);
    float be = beta[c] - mu * sc;

    float4 v = *(float4*)(out + i);
    v.x = fmaxf(v.x * sc + be, 0.f);
    v.y = fmaxf(v.y * sc + be, 0.f);
    v.z = fmaxf(v.z * sc + be, 0.f);
    v.w = fmaxf(v.w * sc + be, 0.f);
    *(float4*)(out + i) = v;
}

// ---------------------------------------------------------------- launch
extern "C" void kernel_launch(void* const* d_in, const int* in_sizes, int n_in,
                              void* d_out, int out_size, void* d_ws, size_t ws_size,
                              hipStream_t stream)
{
    const float* inp   = (const float*)d_in[0];
    const float* fb    = (const float*)d_in[1];
    const float* fc    = (const float*)d_in[2];
    const float* fd    = (const float*)d_in[3];
    const float* Wa    = (const float*)d_in[4];
    const float* Wbm   = (const float*)d_in[5];
    const float* Wcm   = (const float*)d_in[6];
    const float* Wdm   = (const float*)d_in[7];
    const float* fusew = (const float*)d_in[8];
    const float* fuseb = (const float*)d_in[9];
    const float* fgam  = (const float*)d_in[10];
    const float* fbet  = (const float*)d_in[11];
    const float* gcam  = (const float*)d_in[12];
    const float* outw  = (const float*)d_in[13];
    const float* outb  = (const float*)d_in[14];
    const float* ogam  = (const float*)d_in[15];
    const float* obet  = (const float*)d_in[16];

    float* ws    = (float*)d_ws;
    float* apre  = ws + APRE_OFF;
    float* G     = ws + G_OFF;
    float* stats = ws + STATS_OFF;
    float* M2g   = ws + M2_OFF;
    short* mid_t = (short*)((char*)d_ws + MIDT_BYTE);
    short* Wb    = (short*)((char*)d_ws + WB_BYTE);
    float* out   = (float*)d_out;

    hipMemsetAsync(G, 0, (73728ull + 192ull) * sizeof(float), stream);

    k_prep<<<108, 256, 0, stream>>>(outw, Wb);
    k_gram_mfma<<<dim3(144, BATCH), 256, 0, stream>>>(inp, fb, fc, fd, G);
    k_small<<<dim3(4, BATCH), 256, 0, stream>>>(G, Wa, Wbm, Wcm, Wdm, fusew, M2g);
    k_apply_mfma<<<dim3(144, BATCH), 256, 0, stream>>>(inp, fb, fc, fd, M2g, fuseb, apre, stats);
    k_bn1t<<<dim3(576, BATCH), 256, 0, stream>>>(apre, inp, stats, fgam, fbet, gcam, mid_t);
    k_conv_mfma<<<dim3(144, BATCH), 256, 0, stream>>>(mid_t, Wb, outb, out, stats);
    k_bn2<<<13824, 256, 0, stream>>>(out, stats, ogam, obet);
}